// Round 5
// baseline (2817.123 us; speedup 1.0000x reference)
//
#include <hip/hip_runtime.h>

// DETM forward. Round 5: LSTM redesigned UNDER the 128-VGPR cap.
//   R4 post-mortem: 8-wave blocks are hard-capped at 128 VGPRs (launch_bounds
//   (512,1) changed nothing); 200-VGPR weight arrays always spill to scratch
//   (L2-latency-bound, VALUBusy 0.08%). Fix: 1 gate row/thread (100 VGPRs),
//   832 threads (800 active, 13 waves), gates gathered via LDS pg[800].

typedef unsigned int u32;
typedef unsigned short u16;
typedef _Float16 f16;
typedef f16 f16x2 __attribute__((ext_vector_type(2)));
typedef short bf16x8 __attribute__((ext_vector_type(8)));
typedef float f32x4 __attribute__((ext_vector_type(4)));

#define LOG_DELTA (-5.2983174f)
#define COEFF 781.25f   // TRAIN_SIZE / B

__device__ __forceinline__ float bf2f(u16 a) { return __uint_as_float(((u32)a) << 16); }
__device__ __forceinline__ u16 f2bf(float f) {
  u32 u = __float_as_uint(f);
  u32 r = (u + 0x7fffu + ((u >> 16) & 1u)) >> 16;
  return (u16)r;
}
__device__ __forceinline__ float fdot2(u32 w, u32 h, float acc) {
  return __builtin_amdgcn_fdot2(__builtin_bit_cast(f16x2, w), __builtin_bit_cast(f16x2, h), acc, false);
}
__device__ __forceinline__ float sigm(float x) { return 1.f / (1.f + __expf(-x)); }
__device__ __forceinline__ float ftanh(float x) { float t = __expf(2.f * x); return (t - 1.f) / (t + 1.f); }
__device__ __forceinline__ void async_load16(const u16* g, u16* l) {
  __builtin_amdgcn_global_load_lds((const __attribute__((address_space(1))) u32*)g,
                                   (__attribute__((address_space(3))) u32*)l, 16, 0, 0);
}

// ---------------- small utility kernels ----------------

__global__ __launch_bounds__(64) void k_zero(float* __restrict__ accum) {
  if (threadIdx.x < 8) accum[threadIdx.x] = 0.f;
}

__global__ __launch_bounds__(256) void k_nb(const float* __restrict__ bows, float* __restrict__ nb) {
  __shared__ float red[256];
  const int b = blockIdx.x, tid = threadIdx.x;
  float s = 0.f;
  for (int v = tid; v < 10000; v += 256) s += bows[b * 10000 + v];
  red[tid] = s; __syncthreads();
  for (int o = 128; o > 0; o >>= 1) { if (tid < o) red[tid] += red[tid + o]; __syncthreads(); }
  const float inv = 1.f / red[0];
  for (int v = tid; v < 10000; v += 256) nb[b * 10000 + v] = bows[b * 10000 + v] * inv;
}

__global__ __launch_bounds__(256) void k_cvt_f16(const float* __restrict__ w, u16* __restrict__ out, int n) {
  int i = blockIdx.x * 256 + threadIdx.x;
  if (i < n) { f16 h = (f16)w[i]; out[i] = __builtin_bit_cast(u16, h); }
}

__global__ __launch_bounds__(256) void k_bsum(const float* __restrict__ a, const float* __restrict__ b,
                                              float* __restrict__ o, int n) {
  int i = blockIdx.x * 256 + threadIdx.x;
  if (i < n) o[i] = a[i] + b[i];
}

__global__ __launch_bounds__(256) void k_fill(float* __restrict__ C, const float* __restrict__ bias,
                                              int N, int total) {
  for (int i = blockIdx.x * 256 + threadIdx.x; i < total; i += gridDim.x * 256)
    C[i] = bias[i % N];
}

__global__ __launch_bounds__(256) void k_relu(float* __restrict__ C, int total) {
  for (int i = blockIdx.x * 256 + threadIdx.x; i < total; i += gridDim.x * 256) {
    float v = C[i];
    C[i] = v > 0.f ? v : 0.f;
  }
}

// bf16 staging for the beta MFMA GEMM. A: alphas [5120][320] (row m=t*50+k), B: rho [10112][320]
__global__ __launch_bounds__(256) void k_prep_A(const float* __restrict__ muq, u16* __restrict__ Abf) {
  int idx = blockIdx.x * 256 + threadIdx.x;
  if (idx >= 5120 * 320) return;
  int r = idx % 320, m = idx / 320;
  float v = 0.f;
  if (r < 300 && m < 5000) { int t = m / 50, k = m - t * 50; v = muq[k * 30000 + t * 300 + r]; }
  Abf[idx] = f2bf(v);
}
__global__ __launch_bounds__(256) void k_prep_B(const float* __restrict__ rho, u16* __restrict__ Bbf) {
  int idx = blockIdx.x * 256 + threadIdx.x;
  if (idx >= 10112 * 320) return;
  int r = idx % 320, n = idx / 320;
  float v = (r < 300 && n < 10000) ? rho[n * 300 + r] : 0.f;
  Bbf[idx] = f2bf(v);
}

// ---------------- generic fp32 GEMM (small/medium mats): C[M,N] = A[M,K] @ B[N,K]^T ----------------

#define GT 128
#define GBK 16

template<int AMODE, int EPI>
__global__ __launch_bounds__(256) void gemm_abT(
    const float* __restrict__ A, const float* __restrict__ Bm,
    const float* __restrict__ bias, float* __restrict__ C,
    int M, int N, int Kd, int lda, int ldb,
    const int* __restrict__ times, const float* __restrict__ etas)
{
  __shared__ __align__(16) float As[GBK][GT + 4];
  __shared__ __align__(16) float Bs[GBK][GT + 4];
  const int tid = threadIdx.x;
  const int tx = tid & 15, ty = tid >> 4;
  const int m_base = blockIdx.x * GT, n_base = blockIdx.y * GT;
  float acc[8][8] = {};
  const int nkt = (Kd + GBK - 1) / GBK;
  const int per = (nkt + gridDim.z - 1) / gridDim.z;
  const int kt0 = blockIdx.z * per;
  const int kt1 = min(nkt, kt0 + per);
  const int lkk = tid & 15;
  const int lmm = tid >> 4;
  for (int kt = kt0; kt < kt1; ++kt) {
    const int kg = kt * GBK + lkk;
#pragma unroll
    for (int i = 0; i < 8; ++i) {
      int m = m_base + lmm + i * 16;
      float v = 0.f;
      if (m < M && kg < Kd) {
        if (AMODE == 0) v = A[(size_t)m * lda + kg];
        else {
          if (kg < 10000) v = A[(size_t)m * 10000 + kg];
          else v = etas[times[m] * 50 + (kg - 10000)];
        }
      }
      As[lkk][lmm + i * 16] = v;
    }
#pragma unroll
    for (int i = 0; i < 8; ++i) {
      int n = n_base + lmm + i * 16;
      float v = 0.f;
      if (n < N && kg < Kd) v = Bm[(size_t)n * ldb + kg];
      Bs[lkk][lmm + i * 16] = v;
    }
    __syncthreads();
#pragma unroll
    for (int kk = 0; kk < GBK; ++kk) {
      const float4* ap = (const float4*)&As[kk][ty * 8];
      const float4* bp = (const float4*)&Bs[kk][tx * 8];
      float4 a0 = ap[0], a1 = ap[1];
      float4 b0 = bp[0], b1 = bp[1];
      float av[8] = {a0.x, a0.y, a0.z, a0.w, a1.x, a1.y, a1.z, a1.w};
      float bv[8] = {b0.x, b0.y, b0.z, b0.w, b1.x, b1.y, b1.z, b1.w};
#pragma unroll
      for (int i = 0; i < 8; ++i)
#pragma unroll
        for (int j = 0; j < 8; ++j) acc[i][j] += av[i] * bv[j];
    }
    __syncthreads();
  }
#pragma unroll
  for (int i = 0; i < 8; ++i) {
    int m = m_base + ty * 8 + i;
    if (m >= M) continue;
#pragma unroll
    for (int j = 0; j < 8; ++j) {
      int n = n_base + tx * 8 + j;
      if (n >= N) continue;
      float v = acc[i][j];
      if (EPI == 1) { C[(size_t)m * N + n] = v + bias[n]; }
      else if (EPI == 2) { v += bias[n]; C[(size_t)m * N + n] = v > 0.f ? v : 0.f; }
      else if (EPI == 5) { atomicAdd(&C[(size_t)m * N + n], v); }
      else { C[(size_t)m * N + n] = v; }
    }
  }
}

// ---------------- beta GEMM: bf16 MFMA, C[M,N](bf16) = A[M,320] @ B[N,320]^T ----------------

__global__ __launch_bounds__(256) void gemm_mfma_bT(
    const u16* __restrict__ A, const u16* __restrict__ B, u16* __restrict__ C,
    int M, int N)
{
  __shared__ u16 As[128 * 32];
  __shared__ u16 Bs[128 * 32];
  const int tid = threadIdx.x;
  const int l = tid & 63, w = tid >> 6;
  const int wm = w & 1, wn = w >> 1;
  const int m0 = blockIdx.x * 128, n0 = blockIdx.y * 128;
  f32x4 acc[4][4] = {};
  const int arow = l >> 2;
  const int acol = (l & 3) * 8;
  for (int kt = 0; kt < 10; ++kt) {
    const int k0 = kt * 32;
#pragma unroll
    for (int c = 0; c < 2; ++c) {
      const int i = w + c * 4;
      async_load16(A + (size_t)(m0 + i * 16 + arow) * 320 + k0 + acol, As + i * 512);
      async_load16(B + (size_t)(n0 + i * 16 + arow) * 320 + k0 + acol, Bs + i * 512);
    }
    __syncthreads();
    bf16x8 af[4], bfr[4];
#pragma unroll
    for (int x = 0; x < 4; ++x) {
      af[x]  = *(const bf16x8*)&As[(wm * 64 + x * 16 + (l & 15)) * 32 + (l >> 4) * 8];
      bfr[x] = *(const bf16x8*)&Bs[(wn * 64 + x * 16 + (l & 15)) * 32 + (l >> 4) * 8];
    }
#pragma unroll
    for (int x = 0; x < 4; ++x)
#pragma unroll
      for (int y = 0; y < 4; ++y)
        acc[x][y] = __builtin_amdgcn_mfma_f32_16x16x32_bf16(af[x], bfr[y], acc[x][y], 0, 0, 0);
    __syncthreads();
  }
  const int col = l & 15, quad = l >> 4;
#pragma unroll
  for (int x = 0; x < 4; ++x) {
    const int gmB = m0 + wm * 64 + x * 16 + quad * 4;
#pragma unroll
    for (int y = 0; y < 4; ++y) {
      const int gn = n0 + wn * 64 + y * 16 + col;
      if (gn >= N) continue;
#pragma unroll
      for (int r = 0; r < 4; ++r) {
        const int gm = gmB + r;
        if (gm < M) C[(size_t)gm * N + gn] = f2bf(acc[x][y][r]);
      }
    }
  }
}

// ---------------- sequential LSTM scan: 1 gate row / thread, under the 128-VGPR cap ----------------
// 832 threads (13 waves), threads 0..799 active: thread r holds Whh row r as
// 25 uint4 (100 VGPRs, f16). Gates gathered via LDS pg[800]. h broadcast via
// LDS (packed f16x2): same-address b128 reads -> conflict-free broadcast.

__global__ __launch_bounds__(832, 1) void lstm_scan_reg(
    const u16* __restrict__ whh_h, const float* __restrict__ xproj,
    float* __restrict__ hseq,
    const float* __restrict__ muW, const float* __restrict__ mub,
    const float* __restrict__ lsW, const float* __restrict__ lsb,
    float* __restrict__ etas, float* __restrict__ accum, const int do_eta)
{
  __shared__ __align__(16) u32 xh2[104];     // h packed f16x2
  __shared__ __align__(16) float xcat[252];  // [0..199]=h f32, [200..249]=eta_prev
  __shared__ float pg[800];                  // gate pre-activations
  __shared__ float pc[400];
  __shared__ float mu_ls[100];
  const int tid = threadIdx.x;
  const int act = (tid < 800);
  const int row = tid;                       // gate row (valid if act)
  const int u = tid % 200;                   // hidden unit for cell phase
  uint4 wr[25];
  if (act) {
    const uint4* W4 = (const uint4*)whh_h;   // 25 uint4 per row
#pragma unroll
    for (int c = 0; c < 25; ++c) wr[c] = W4[row * 25 + c];
  }
  if (tid < 104) xh2[tid] = 0u;
  if (tid < 252) xcat[tid] = 0.f;
  float c_reg = 0.f, klacc = 0.f;
  __syncthreads();
  for (int t = 0; t < 100; ++t) {
    if (act) {
      const float xp = xproj[t * 800 + row];   // issue early; used at end
      float a0 = 0.f, a1 = 0.f;                // two dep chains
      const uint4* H4 = (const uint4*)xh2;
#pragma unroll
      for (int g = 0; g < 13; ++g) {
#pragma unroll
        for (int c2 = 0; c2 < 2; ++c2) {
          const int c = g * 2 + c2;
          if (c < 25) {
            uint4 hv = H4[c];
            if (c2) {
              a1 = fdot2(wr[c].x, hv.x, a1); a1 = fdot2(wr[c].y, hv.y, a1);
              a1 = fdot2(wr[c].z, hv.z, a1); a1 = fdot2(wr[c].w, hv.w, a1);
            } else {
              a0 = fdot2(wr[c].x, hv.x, a0); a0 = fdot2(wr[c].y, hv.y, a0);
              a0 = fdot2(wr[c].z, hv.z, a0); a0 = fdot2(wr[c].w, hv.w, a0);
            }
          }
        }
        __builtin_amdgcn_sched_barrier(0);   // <=2 live hv chunks: stay under 128 VGPRs
      }
      pg[row] = a0 + a1 + xp;
    }
    __syncthreads();   // gates visible; all dots done reading old h
    if (tid < 200) {
      float gi = sigm(pg[u]);
      float gf = sigm(pg[200 + u]);
      float gg = ftanh(pg[400 + u]);
      float go = sigm(pg[600 + u]);
      c_reg = gf * c_reg + gi * gg;
      float hv = go * ftanh(c_reg);
      xcat[u] = hv;
      ((u16*)xh2)[u] = __builtin_bit_cast(u16, (f16)hv);
      if (!do_eta) hseq[t * 200 + u] = hv;
    }
    __syncthreads();   // new h visible for next step / eta matvec
    if (do_eta) {
      if (tid < 400) {
        const int k100 = tid >> 2, s4 = tid & 3;
        const float* Wr = (k100 < 50) ? (muW + k100 * 250) : (lsW + (k100 - 50) * 250);
        const float2* Wr2 = (const float2*)Wr;
        const float2* X2 = (const float2*)xcat;
        const int p0 = s4 * 32;
        const int p1 = min(125, p0 + 32);
        float p = 0.f;
        for (int q = p0; q < p1; ++q) { float2 w2 = Wr2[q]; float2 x2 = X2[q]; p += w2.x * x2.x + w2.y * x2.y; }
        pc[tid] = p;
      }
      __syncthreads();
      if (tid < 100) {
        float v = pc[tid * 4] + pc[tid * 4 + 1] + pc[tid * 4 + 2] + pc[tid * 4 + 3];
        v += (tid < 50) ? mub[tid] : lsb[tid - 50];
        mu_ls[tid] = v;
      }
      __syncthreads();
      if (tid < 50) {
        float mu = mu_ls[tid], ls = mu_ls[50 + tid], ep = xcat[200 + tid];
        float pls = (t == 0) ? 0.f : LOG_DELTA;
        float pv = __expf(pls) + 1e-6f;
        float d = mu - ep;
        klacc += 0.5f * ((__expf(ls) + d * d) / pv - 1.f + pls - ls);
        xcat[200 + tid] = mu;
        etas[t * 50 + tid] = mu;
      }
      __syncthreads();
    }
  }
  if (do_eta) {
    if (tid < 50) pg[tid] = klacc;
    __syncthreads();
    if (tid == 0) { float ss = 0.f; for (int i = 0; i < 50; ++i) ss += pg[i]; accum[0] = ss; }
  }
}

// ---------------- theta head ----------------

__global__ __launch_bounds__(64) void k_theta(const float* __restrict__ mu_t, const float* __restrict__ ls_t,
                                              const float* __restrict__ etas, const int* __restrict__ times,
                                              float* __restrict__ theta, float* __restrict__ accum) {
  const int b = blockIdx.x, lane = threadIdx.x;
  float m_ = 0.f, l_ = 0.f, e_ = 0.f, mx = -1e30f;
  if (lane < 50) {
    m_ = mu_t[b * 50 + lane];
    l_ = ls_t[b * 50 + lane];
    e_ = etas[times[b] * 50 + lane];
    mx = m_;
  }
  for (int o = 32; o > 0; o >>= 1) mx = fmaxf(mx, __shfl_down(mx, o));
  mx = __shfl(mx, 0);
  float ex = (lane < 50) ? __expf(m_ - mx) : 0.f;
  float sum = ex;
  for (int o = 32; o > 0; o >>= 1) sum += __shfl_down(sum, o);
  sum = __shfl(sum, 0);
  if (lane < 50) theta[b * 50 + lane] = ex / sum;
  float kl = 0.f;
  if (lane < 50) {
    float d = m_ - e_;
    kl = 0.5f * ((__expf(l_) + d * d) / (1.f + 1e-6f) - 1.f - l_);
  }
  for (int o = 32; o > 0; o >>= 1) kl += __shfl_down(kl, o);
  if (lane == 0) atomicAdd(accum + 1, kl);
}

// ---------------- softmax denominators (no max-shift; |logit| small) ----------------

__global__ __launch_bounds__(256) void k_rowsum(const u16* __restrict__ logit, float* __restrict__ Z) {
  const int r = blockIdx.x, tid = threadIdx.x;
  const u32* row = (const u32*)(logit + (size_t)r * 10000);
  __shared__ float red[256];
  float s = 0.f;
  for (int v = tid; v < 5000; v += 256) {
    u32 p = row[v];
    s += __expf(bf2f((u16)(p & 0xffffu))) + __expf(bf2f((u16)(p >> 16)));
  }
  red[tid] = s; __syncthreads();
  for (int o = 128; o > 0; o >>= 1) { if (tid < o) red[tid] += red[tid + o]; __syncthreads(); }
  if (tid == 0) Z[r] = red[0];
}

// ---------------- NLL ----------------

__global__ __launch_bounds__(256) void k_nll(const u16* __restrict__ logit, const float* __restrict__ Z,
                                             const float* __restrict__ theta, const float* __restrict__ bows,
                                             const int* __restrict__ times, float* __restrict__ accum) {
  const int b = blockIdx.x, seg = blockIdx.y, tid = threadIdx.x;
  const int t = times[b];
  __shared__ float c2[52];
  __shared__ float red[256];
  if (tid < 50) c2[tid] = theta[b * 50 + tid] / Z[t * 50 + tid];
  __syncthreads();
  float part = 0.f;
  const int v0 = seg * 1250, v1 = v0 + 1250;
  const u16* base = logit + (size_t)t * 500000;
  for (int v = v0 + tid; v < v1; v += 256) {
    float ssv = 1e-12f;
#pragma unroll
    for (int k = 0; k < 50; ++k) ssv += c2[k] * __expf(bf2f(base[k * 10000 + v]));
    part += bows[b * 10000 + v] * __logf(ssv);
  }
  red[tid] = part; __syncthreads();
  for (int o = 128; o > 0; o >>= 1) { if (tid < o) red[tid] += red[tid + o]; __syncthreads(); }
  if (tid == 0) atomicAdd(accum + 3, -red[0]);
}

// ---------------- kl_alpha ----------------

__global__ __launch_bounds__(256) void k_alpha_kl(const float* __restrict__ muq, const float* __restrict__ lsq,
                                                  float* __restrict__ accum) {
  __shared__ float red[256];
  const int tid = threadIdx.x;
  float s = 0.f;
  for (int i = blockIdx.x * 256 + tid; i < 1500000; i += gridDim.x * 256) {
    int r = i % 300;
    int tk = i / 300;
    int k = tk % 50;
    int t = tk / 50;
    size_t idx = (size_t)k * 30000 + (size_t)t * 300 + r;
    float mu = muq[idx], ls = lsq[idx];
    float pm = 0.f, pls = 0.f;
    if (t > 0) { pm = muq[idx - 300]; pls = LOG_DELTA; }
    float d = mu - pm;
    s += 0.5f * ((__expf(ls) + d * d) / (__expf(pls) + 1e-6f) - 1.f + pls - ls);
  }
  red[tid] = s; __syncthreads();
  for (int o = 128; o > 0; o >>= 1) { if (tid < o) red[tid] += red[tid + o]; __syncthreads(); }
  if (tid == 0) atomicAdd(accum + 2, red[0]);
}

// ---------------- final combine ----------------

__global__ __launch_bounds__(64) void k_final(const float* __restrict__ accum, float* __restrict__ out) {
  if (threadIdx.x == 0) {
    float nll = accum[3] * COEFF;
    float kl_eta = accum[0];
    float kl_theta = accum[1] * COEFF;
    float kl_alpha = accum[2];
    out[0] = nll + kl_eta + kl_theta + kl_alpha;
    out[1] = nll;
    out[2] = kl_eta;
    out[3] = kl_theta;
    out[4] = kl_alpha;
  }
}

// ---------------- launcher ----------------

extern "C" void kernel_launch(void* const* d_in, const int* in_sizes, int n_in,
                              void* d_out, int out_size, void* d_ws, size_t ws_size,
                              hipStream_t stream) {
  (void)in_sizes; (void)n_in; (void)out_size; (void)ws_size;
  const float* bows   = (const float*)d_in[0];
  const int*   times  = (const int*)d_in[1];
  const float* rnn_in = (const float*)d_in[2];
  const float* rho_W  = (const float*)d_in[3];
  const float* muq    = (const float*)d_in[4];
  const float* lsq    = (const float*)d_in[5];
  const float* qW1    = (const float*)d_in[6];
  const float* qb1    = (const float*)d_in[7];
  const float* qW2    = (const float*)d_in[8];
  const float* qb2    = (const float*)d_in[9];
  const float* muthW  = (const float*)d_in[10];
  const float* muthb  = (const float*)d_in[11];
  const float* lsthW  = (const float*)d_in[12];
  const float* lsthb  = (const float*)d_in[13];
  const float* emW    = (const float*)d_in[14];
  const float* emb    = (const float*)d_in[15];
  const float* Wih    = (const float*)d_in[16];
  const float* Whh    = (const float*)d_in[17];
  const float* bih    = (const float*)d_in[18];
  const float* bhh    = (const float*)d_in[19];
  const float* mueW   = (const float*)d_in[20];
  const float* mueb   = (const float*)d_in[21];
  const float* lseW   = (const float*)d_in[22];
  const float* lseb   = (const float*)d_in[23];
  float* out = (float*)d_out;
  float* ws = (float*)d_ws;

  float* accum = ws + 0;
  float* nb    = ws + 8;
  float* x0    = ws + 1280008;
  float* xproj = ws + 1300008;
  float* hsA   = ws + 1380008;
  float* hsB   = ws + 1400008;
  u16*   whhh  = (u16*)(ws + 1420008);
  float* bsum  = ws + 1660008;
  float* etas  = ws + 1662408;
  float* h1    = ws + 1667408;
  float* h2    = ws + 1769808;
  float* mu_t  = ws + 1872208;
  float* ls_t  = ws + 1878608;
  float* theta = ws + 1885008;
  float* Zrow  = ws + 1891408;
  u16*   A_bf  = (u16*)(ws + 1896408);
  u16*   B_bf  = (u16*)(ws + 2715608);
  u16*   logit = (u16*)(ws + 4333528);

  k_zero<<<1, 64, 0, stream>>>(accum);
  k_nb<<<128, 256, 0, stream>>>(bows, nb);
  k_cvt_f16<<<1875, 256, 0, stream>>>(Whh, whhh, 480000);
  k_bsum<<<10, 256, 0, stream>>>(bih, bhh, bsum, 2400);
  k_prep_A<<<6400, 256, 0, stream>>>(muq, A_bf);
  k_prep_B<<<12640, 256, 0, stream>>>(rho_W, B_bf);

  // x0 = rnn_inp @ eta_map_W^T + eta_map_b
  k_fill<<<79, 256, 0, stream>>>(x0, emb, 200, 20000);
  gemm_abT<0, 5><<<dim3(1, 2, 16), 256, 0, stream>>>(rnn_in, emW, nullptr, x0,
                                                     100, 200, 10000, 10000, 10000, nullptr, nullptr);

  // LSTM layers
  const float* lin[3] = {x0, hsA, hsB};
  float* lout[3] = {hsA, hsB, hsA};
  for (int l = 0; l < 3; ++l) {
    gemm_abT<0, 1><<<dim3(1, 7, 1), 256, 0, stream>>>(lin[l], Wih + l * 160000, bsum + l * 800,
                                                      xproj, 100, 800, 200, 200, 200,
                                                      nullptr, nullptr);
    lstm_scan_reg<<<1, 832, 0, stream>>>(whhh + l * 160000, xproj, lout[l],
                                         mueW, mueb, lseW, lseb, etas, accum, (l == 2) ? 1 : 0);
  }

  // theta encoder
  k_fill<<<400, 256, 0, stream>>>(h1, qb1, 800, 102400);
  gemm_abT<2, 5><<<dim3(1, 7, 24), 256, 0, stream>>>(nb, qW1, nullptr, h1,
                                                     128, 800, 10050, 10000, 10050, times, etas);
  k_relu<<<400, 256, 0, stream>>>(h1, 102400);
  gemm_abT<0, 2><<<dim3(1, 7, 1), 256, 0, stream>>>(h1, qW2, qb2, h2,
                                                    128, 800, 800, 800, 800, nullptr, nullptr);
  gemm_abT<0, 1><<<dim3(1, 1, 1), 256, 0, stream>>>(h2, muthW, muthb, mu_t,
                                                    128, 50, 800, 800, 800, nullptr, nullptr);
  gemm_abT<0, 1><<<dim3(1, 1, 1), 256, 0, stream>>>(h2, lsthW, lsthb, ls_t,
                                                    128, 50, 800, 800, 800, nullptr, nullptr);
  k_theta<<<128, 64, 0, stream>>>(mu_t, ls_t, etas, times, theta, accum);

  // beta logits (bf16 MFMA) + softmax denominators + NLL
  gemm_mfma_bT<<<dim3(40, 79), 256, 0, stream>>>(A_bf, B_bf, logit, 5000, 10000);
  k_rowsum<<<5000, 256, 0, stream>>>(logit, Zrow);
  k_nll<<<dim3(128, 8), 256, 0, stream>>>(logit, Zrow, theta, bows, times, accum);

  k_alpha_kl<<<512, 256, 0, stream>>>(muq, lsq, accum);
  k_final<<<1, 64, 0, stream>>>(accum, out);
}

// Round 6
// 2769.654 us; speedup vs baseline: 1.0171x; 1.0171x over previous
//
#include <hip/hip_runtime.h>

// DETM forward. Round 6: force the VGPR budget with amdgpu_waves_per_eu.
//   R5 post-mortem: 832-thr block => allocator targets 8 waves/EU => 64-VGPR
//   budget => 100-VGPR weight array spilled (VGPR_Count=64, dur unchanged).
//   __launch_bounds__' 2nd arg never moved the target (R3-R5). Fix: pin
//   amdgpu_waves_per_eu(4,4) => budget 512/4 = 128 >= demand ~118.

typedef unsigned int u32;
typedef unsigned short u16;
typedef _Float16 f16;
typedef f16 f16x2 __attribute__((ext_vector_type(2)));
typedef short bf16x8 __attribute__((ext_vector_type(8)));
typedef float f32x4 __attribute__((ext_vector_type(4)));

#define LOG_DELTA (-5.2983174f)
#define COEFF 781.25f   // TRAIN_SIZE / B

__device__ __forceinline__ float bf2f(u16 a) { return __uint_as_float(((u32)a) << 16); }
__device__ __forceinline__ u16 f2bf(float f) {
  u32 u = __float_as_uint(f);
  u32 r = (u + 0x7fffu + ((u >> 16) & 1u)) >> 16;
  return (u16)r;
}
__device__ __forceinline__ float fdot2(u32 w, u32 h, float acc) {
  return __builtin_amdgcn_fdot2(__builtin_bit_cast(f16x2, w), __builtin_bit_cast(f16x2, h), acc, false);
}
__device__ __forceinline__ float sigm(float x) { return 1.f / (1.f + __expf(-x)); }
__device__ __forceinline__ float ftanh(float x) { float t = __expf(2.f * x); return (t - 1.f) / (t + 1.f); }
__device__ __forceinline__ void async_load16(const u16* g, u16* l) {
  __builtin_amdgcn_global_load_lds((const __attribute__((address_space(1))) u32*)g,
                                   (__attribute__((address_space(3))) u32*)l, 16, 0, 0);
}

// ---------------- small utility kernels ----------------

__global__ __launch_bounds__(64) void k_zero(float* __restrict__ accum) {
  if (threadIdx.x < 8) accum[threadIdx.x] = 0.f;
}

__global__ __launch_bounds__(256) void k_nb(const float* __restrict__ bows, float* __restrict__ nb) {
  __shared__ float red[256];
  const int b = blockIdx.x, tid = threadIdx.x;
  float s = 0.f;
  for (int v = tid; v < 10000; v += 256) s += bows[b * 10000 + v];
  red[tid] = s; __syncthreads();
  for (int o = 128; o > 0; o >>= 1) { if (tid < o) red[tid] += red[tid + o]; __syncthreads(); }
  const float inv = 1.f / red[0];
  for (int v = tid; v < 10000; v += 256) nb[b * 10000 + v] = bows[b * 10000 + v] * inv;
}

__global__ __launch_bounds__(256) void k_cvt_f16(const float* __restrict__ w, u16* __restrict__ out, int n) {
  int i = blockIdx.x * 256 + threadIdx.x;
  if (i < n) { f16 h = (f16)w[i]; out[i] = __builtin_bit_cast(u16, h); }
}

__global__ __launch_bounds__(256) void k_bsum(const float* __restrict__ a, const float* __restrict__ b,
                                              float* __restrict__ o, int n) {
  int i = blockIdx.x * 256 + threadIdx.x;
  if (i < n) o[i] = a[i] + b[i];
}

__global__ __launch_bounds__(256) void k_fill(float* __restrict__ C, const float* __restrict__ bias,
                                              int N, int total) {
  for (int i = blockIdx.x * 256 + threadIdx.x; i < total; i += gridDim.x * 256)
    C[i] = bias[i % N];
}

__global__ __launch_bounds__(256) void k_relu(float* __restrict__ C, int total) {
  for (int i = blockIdx.x * 256 + threadIdx.x; i < total; i += gridDim.x * 256) {
    float v = C[i];
    C[i] = v > 0.f ? v : 0.f;
  }
}

// bf16 staging for the beta MFMA GEMM. A: alphas [5120][320] (row m=t*50+k), B: rho [10112][320]
__global__ __launch_bounds__(256) void k_prep_A(const float* __restrict__ muq, u16* __restrict__ Abf) {
  int idx = blockIdx.x * 256 + threadIdx.x;
  if (idx >= 5120 * 320) return;
  int r = idx % 320, m = idx / 320;
  float v = 0.f;
  if (r < 300 && m < 5000) { int t = m / 50, k = m - t * 50; v = muq[k * 30000 + t * 300 + r]; }
  Abf[idx] = f2bf(v);
}
__global__ __launch_bounds__(256) void k_prep_B(const float* __restrict__ rho, u16* __restrict__ Bbf) {
  int idx = blockIdx.x * 256 + threadIdx.x;
  if (idx >= 10112 * 320) return;
  int r = idx % 320, n = idx / 320;
  float v = (r < 300 && n < 10000) ? rho[n * 300 + r] : 0.f;
  Bbf[idx] = f2bf(v);
}

// ---------------- generic fp32 GEMM (small/medium mats): C[M,N] = A[M,K] @ B[N,K]^T ----------------

#define GT 128
#define GBK 16

template<int AMODE, int EPI>
__global__ __launch_bounds__(256) void gemm_abT(
    const float* __restrict__ A, const float* __restrict__ Bm,
    const float* __restrict__ bias, float* __restrict__ C,
    int M, int N, int Kd, int lda, int ldb,
    const int* __restrict__ times, const float* __restrict__ etas)
{
  __shared__ __align__(16) float As[GBK][GT + 4];
  __shared__ __align__(16) float Bs[GBK][GT + 4];
  const int tid = threadIdx.x;
  const int tx = tid & 15, ty = tid >> 4;
  const int m_base = blockIdx.x * GT, n_base = blockIdx.y * GT;
  float acc[8][8] = {};
  const int nkt = (Kd + GBK - 1) / GBK;
  const int per = (nkt + gridDim.z - 1) / gridDim.z;
  const int kt0 = blockIdx.z * per;
  const int kt1 = min(nkt, kt0 + per);
  const int lkk = tid & 15;
  const int lmm = tid >> 4;
  for (int kt = kt0; kt < kt1; ++kt) {
    const int kg = kt * GBK + lkk;
#pragma unroll
    for (int i = 0; i < 8; ++i) {
      int m = m_base + lmm + i * 16;
      float v = 0.f;
      if (m < M && kg < Kd) {
        if (AMODE == 0) v = A[(size_t)m * lda + kg];
        else {
          if (kg < 10000) v = A[(size_t)m * 10000 + kg];
          else v = etas[times[m] * 50 + (kg - 10000)];
        }
      }
      As[lkk][lmm + i * 16] = v;
    }
#pragma unroll
    for (int i = 0; i < 8; ++i) {
      int n = n_base + lmm + i * 16;
      float v = 0.f;
      if (n < N && kg < Kd) v = Bm[(size_t)n * ldb + kg];
      Bs[lkk][lmm + i * 16] = v;
    }
    __syncthreads();
#pragma unroll
    for (int kk = 0; kk < GBK; ++kk) {
      const float4* ap = (const float4*)&As[kk][ty * 8];
      const float4* bp = (const float4*)&Bs[kk][tx * 8];
      float4 a0 = ap[0], a1 = ap[1];
      float4 b0 = bp[0], b1 = bp[1];
      float av[8] = {a0.x, a0.y, a0.z, a0.w, a1.x, a1.y, a1.z, a1.w};
      float bv[8] = {b0.x, b0.y, b0.z, b0.w, b1.x, b1.y, b1.z, b1.w};
#pragma unroll
      for (int i = 0; i < 8; ++i)
#pragma unroll
        for (int j = 0; j < 8; ++j) acc[i][j] += av[i] * bv[j];
    }
    __syncthreads();
  }
#pragma unroll
  for (int i = 0; i < 8; ++i) {
    int m = m_base + ty * 8 + i;
    if (m >= M) continue;
#pragma unroll
    for (int j = 0; j < 8; ++j) {
      int n = n_base + tx * 8 + j;
      if (n >= N) continue;
      float v = acc[i][j];
      if (EPI == 1) { C[(size_t)m * N + n] = v + bias[n]; }
      else if (EPI == 2) { v += bias[n]; C[(size_t)m * N + n] = v > 0.f ? v : 0.f; }
      else if (EPI == 5) { atomicAdd(&C[(size_t)m * N + n], v); }
      else { C[(size_t)m * N + n] = v; }
    }
  }
}

// ---------------- beta GEMM: bf16 MFMA, C[M,N](bf16) = A[M,320] @ B[N,320]^T ----------------

__global__ __launch_bounds__(256) void gemm_mfma_bT(
    const u16* __restrict__ A, const u16* __restrict__ B, u16* __restrict__ C,
    int M, int N)
{
  __shared__ u16 As[128 * 32];
  __shared__ u16 Bs[128 * 32];
  const int tid = threadIdx.x;
  const int l = tid & 63, w = tid >> 6;
  const int wm = w & 1, wn = w >> 1;
  const int m0 = blockIdx.x * 128, n0 = blockIdx.y * 128;
  f32x4 acc[4][4] = {};
  const int arow = l >> 2;
  const int acol = (l & 3) * 8;
  for (int kt = 0; kt < 10; ++kt) {
    const int k0 = kt * 32;
#pragma unroll
    for (int c = 0; c < 2; ++c) {
      const int i = w + c * 4;
      async_load16(A + (size_t)(m0 + i * 16 + arow) * 320 + k0 + acol, As + i * 512);
      async_load16(B + (size_t)(n0 + i * 16 + arow) * 320 + k0 + acol, Bs + i * 512);
    }
    __syncthreads();
    bf16x8 af[4], bfr[4];
#pragma unroll
    for (int x = 0; x < 4; ++x) {
      af[x]  = *(const bf16x8*)&As[(wm * 64 + x * 16 + (l & 15)) * 32 + (l >> 4) * 8];
      bfr[x] = *(const bf16x8*)&Bs[(wn * 64 + x * 16 + (l & 15)) * 32 + (l >> 4) * 8];
    }
#pragma unroll
    for (int x = 0; x < 4; ++x)
#pragma unroll
      for (int y = 0; y < 4; ++y)
        acc[x][y] = __builtin_amdgcn_mfma_f32_16x16x32_bf16(af[x], bfr[y], acc[x][y], 0, 0, 0);
    __syncthreads();
  }
  const int col = l & 15, quad = l >> 4;
#pragma unroll
  for (int x = 0; x < 4; ++x) {
    const int gmB = m0 + wm * 64 + x * 16 + quad * 4;
#pragma unroll
    for (int y = 0; y < 4; ++y) {
      const int gn = n0 + wn * 64 + y * 16 + col;
      if (gn >= N) continue;
#pragma unroll
      for (int r = 0; r < 4; ++r) {
        const int gm = gmB + r;
        if (gm < M) C[(size_t)gm * N + gn] = f2bf(acc[x][y][r]);
      }
    }
  }
}

// ---------------- sequential LSTM scan: 1 gate row / thread, 128-VGPR budget pinned ----------------
// 832 threads (13 waves), threads 0..799 active: thread r holds Whh row r as
// 25 uint4 (100 VGPRs, f16). amdgpu_waves_per_eu(4,4) pins the register budget
// to 512/4 = 128 so the weight array stays register-resident (no spill).

__global__ __attribute__((amdgpu_flat_work_group_size(832, 832)))
__attribute__((amdgpu_waves_per_eu(4, 4))) void lstm_scan_reg(
    const u16* __restrict__ whh_h, const float* __restrict__ xproj,
    float* __restrict__ hseq,
    const float* __restrict__ muW, const float* __restrict__ mub,
    const float* __restrict__ lsW, const float* __restrict__ lsb,
    float* __restrict__ etas, float* __restrict__ accum, const int do_eta)
{
  __shared__ __align__(16) u32 xh2[104];     // h packed f16x2
  __shared__ __align__(16) float xcat[252];  // [0..199]=h f32, [200..249]=eta_prev
  __shared__ float pg[800];                  // gate pre-activations
  __shared__ float pc[400];
  __shared__ float mu_ls[100];
  const int tid = threadIdx.x;
  const int act = (tid < 800);
  const int row = tid;                       // gate row (valid if act)
  const int u = tid % 200;                   // hidden unit for cell phase
  uint4 wr[25];
  if (act) {
    const uint4* W4 = (const uint4*)whh_h;   // 25 uint4 per row
#pragma unroll
    for (int c = 0; c < 25; ++c) wr[c] = W4[row * 25 + c];
  }
  if (tid < 104) xh2[tid] = 0u;
  if (tid < 252) xcat[tid] = 0.f;
  float c_reg = 0.f, klacc = 0.f;
  __syncthreads();
  for (int t = 0; t < 100; ++t) {
    if (act) {
      const float xp = xproj[t * 800 + row];   // issue early; used at end
      float a0 = 0.f, a1 = 0.f;                // two dep chains
      const uint4* H4 = (const uint4*)xh2;
#pragma unroll
      for (int g = 0; g < 13; ++g) {
#pragma unroll
        for (int c2 = 0; c2 < 2; ++c2) {
          const int c = g * 2 + c2;
          if (c < 25) {
            uint4 hv = H4[c];
            if (c2) {
              a1 = fdot2(wr[c].x, hv.x, a1); a1 = fdot2(wr[c].y, hv.y, a1);
              a1 = fdot2(wr[c].z, hv.z, a1); a1 = fdot2(wr[c].w, hv.w, a1);
            } else {
              a0 = fdot2(wr[c].x, hv.x, a0); a0 = fdot2(wr[c].y, hv.y, a0);
              a0 = fdot2(wr[c].z, hv.z, a0); a0 = fdot2(wr[c].w, hv.w, a0);
            }
          }
        }
        __builtin_amdgcn_sched_barrier(0);   // <=2 live hv chunks: cap pressure
      }
      pg[row] = a0 + a1 + xp;
    }
    __syncthreads();   // gates visible; all dots done reading old h
    if (tid < 200) {
      float gi = sigm(pg[u]);
      float gf = sigm(pg[200 + u]);
      float gg = ftanh(pg[400 + u]);
      float go = sigm(pg[600 + u]);
      c_reg = gf * c_reg + gi * gg;
      float hv = go * ftanh(c_reg);
      xcat[u] = hv;
      ((u16*)xh2)[u] = __builtin_bit_cast(u16, (f16)hv);
      if (!do_eta) hseq[t * 200 + u] = hv;
    }
    __syncthreads();   // new h visible for next step / eta matvec
    if (do_eta) {
      if (tid < 400) {
        const int k100 = tid >> 2, s4 = tid & 3;
        const float* Wr = (k100 < 50) ? (muW + k100 * 250) : (lsW + (k100 - 50) * 250);
        const float2* Wr2 = (const float2*)Wr;
        const float2* X2 = (const float2*)xcat;
        const int p0 = s4 * 32;
        const int p1 = min(125, p0 + 32);
        float p = 0.f;
        for (int q = p0; q < p1; ++q) { float2 w2 = Wr2[q]; float2 x2 = X2[q]; p += w2.x * x2.x + w2.y * x2.y; }
        pc[tid] = p;
      }
      __syncthreads();
      if (tid < 100) {
        float v = pc[tid * 4] + pc[tid * 4 + 1] + pc[tid * 4 + 2] + pc[tid * 4 + 3];
        v += (tid < 50) ? mub[tid] : lsb[tid - 50];
        mu_ls[tid] = v;
      }
      __syncthreads();
      if (tid < 50) {
        float mu = mu_ls[tid], ls = mu_ls[50 + tid], ep = xcat[200 + tid];
        float pls = (t == 0) ? 0.f : LOG_DELTA;
        float pv = __expf(pls) + 1e-6f;
        float d = mu - ep;
        klacc += 0.5f * ((__expf(ls) + d * d) / pv - 1.f + pls - ls);
        xcat[200 + tid] = mu;
        etas[t * 50 + tid] = mu;
      }
      __syncthreads();
    }
  }
  if (do_eta) {
    if (tid < 50) pg[tid] = klacc;
    __syncthreads();
    if (tid == 0) { float ss = 0.f; for (int i = 0; i < 50; ++i) ss += pg[i]; accum[0] = ss; }
  }
}

// ---------------- theta head ----------------

__global__ __launch_bounds__(64) void k_theta(const float* __restrict__ mu_t, const float* __restrict__ ls_t,
                                              const float* __restrict__ etas, const int* __restrict__ times,
                                              float* __restrict__ theta, float* __restrict__ accum) {
  const int b = blockIdx.x, lane = threadIdx.x;
  float m_ = 0.f, l_ = 0.f, e_ = 0.f, mx = -1e30f;
  if (lane < 50) {
    m_ = mu_t[b * 50 + lane];
    l_ = ls_t[b * 50 + lane];
    e_ = etas[times[b] * 50 + lane];
    mx = m_;
  }
  for (int o = 32; o > 0; o >>= 1) mx = fmaxf(mx, __shfl_down(mx, o));
  mx = __shfl(mx, 0);
  float ex = (lane < 50) ? __expf(m_ - mx) : 0.f;
  float sum = ex;
  for (int o = 32; o > 0; o >>= 1) sum += __shfl_down(sum, o);
  sum = __shfl(sum, 0);
  if (lane < 50) theta[b * 50 + lane] = ex / sum;
  float kl = 0.f;
  if (lane < 50) {
    float d = m_ - e_;
    kl = 0.5f * ((__expf(l_) + d * d) / (1.f + 1e-6f) - 1.f - l_);
  }
  for (int o = 32; o > 0; o >>= 1) kl += __shfl_down(kl, o);
  if (lane == 0) atomicAdd(accum + 1, kl);
}

// ---------------- softmax denominators (no max-shift; |logit| small) ----------------

__global__ __launch_bounds__(256) void k_rowsum(const u16* __restrict__ logit, float* __restrict__ Z) {
  const int r = blockIdx.x, tid = threadIdx.x;
  const u32* row = (const u32*)(logit + (size_t)r * 10000);
  __shared__ float red[256];
  float s = 0.f;
  for (int v = tid; v < 5000; v += 256) {
    u32 p = row[v];
    s += __expf(bf2f((u16)(p & 0xffffu))) + __expf(bf2f((u16)(p >> 16)));
  }
  red[tid] = s; __syncthreads();
  for (int o = 128; o > 0; o >>= 1) { if (tid < o) red[tid] += red[tid + o]; __syncthreads(); }
  if (tid == 0) Z[r] = red[0];
}

// ---------------- NLL ----------------

__global__ __launch_bounds__(256) void k_nll(const u16* __restrict__ logit, const float* __restrict__ Z,
                                             const float* __restrict__ theta, const float* __restrict__ bows,
                                             const int* __restrict__ times, float* __restrict__ accum) {
  const int b = blockIdx.x, seg = blockIdx.y, tid = threadIdx.x;
  const int t = times[b];
  __shared__ float c2[52];
  __shared__ float red[256];
  if (tid < 50) c2[tid] = theta[b * 50 + tid] / Z[t * 50 + tid];
  __syncthreads();
  float part = 0.f;
  const int v0 = seg * 1250, v1 = v0 + 1250;
  const u16* base = logit + (size_t)t * 500000;
  for (int v = v0 + tid; v < v1; v += 256) {
    float ssv = 1e-12f;
#pragma unroll
    for (int k = 0; k < 50; ++k) ssv += c2[k] * __expf(bf2f(base[k * 10000 + v]));
    part += bows[b * 10000 + v] * __logf(ssv);
  }
  red[tid] = part; __syncthreads();
  for (int o = 128; o > 0; o >>= 1) { if (tid < o) red[tid] += red[tid + o]; __syncthreads(); }
  if (tid == 0) atomicAdd(accum + 3, -red[0]);
}

// ---------------- kl_alpha ----------------

__global__ __launch_bounds__(256) void k_alpha_kl(const float* __restrict__ muq, const float* __restrict__ lsq,
                                                  float* __restrict__ accum) {
  __shared__ float red[256];
  const int tid = threadIdx.x;
  float s = 0.f;
  for (int i = blockIdx.x * 256 + tid; i < 1500000; i += gridDim.x * 256) {
    int r = i % 300;
    int tk = i / 300;
    int k = tk % 50;
    int t = tk / 50;
    size_t idx = (size_t)k * 30000 + (size_t)t * 300 + r;
    float mu = muq[idx], ls = lsq[idx];
    float pm = 0.f, pls = 0.f;
    if (t > 0) { pm = muq[idx - 300]; pls = LOG_DELTA; }
    float d = mu - pm;
    s += 0.5f * ((__expf(ls) + d * d) / (__expf(pls) + 1e-6f) - 1.f + pls - ls);
  }
  red[tid] = s; __syncthreads();
  for (int o = 128; o > 0; o >>= 1) { if (tid < o) red[tid] += red[tid + o]; __syncthreads(); }
  if (tid == 0) atomicAdd(accum + 2, red[0]);
}

// ---------------- final combine ----------------

__global__ __launch_bounds__(64) void k_final(const float* __restrict__ accum, float* __restrict__ out) {
  if (threadIdx.x == 0) {
    float nll = accum[3] * COEFF;
    float kl_eta = accum[0];
    float kl_theta = accum[1] * COEFF;
    float kl_alpha = accum[2];
    out[0] = nll + kl_eta + kl_theta + kl_alpha;
    out[1] = nll;
    out[2] = kl_eta;
    out[3] = kl_theta;
    out[4] = kl_alpha;
  }
}

// ---------------- launcher ----------------

extern "C" void kernel_launch(void* const* d_in, const int* in_sizes, int n_in,
                              void* d_out, int out_size, void* d_ws, size_t ws_size,
                              hipStream_t stream) {
  (void)in_sizes; (void)n_in; (void)out_size; (void)ws_size;
  const float* bows   = (const float*)d_in[0];
  const int*   times  = (const int*)d_in[1];
  const float* rnn_in = (const float*)d_in[2];
  const float* rho_W  = (const float*)d_in[3];
  const float* muq    = (const float*)d_in[4];
  const float* lsq    = (const float*)d_in[5];
  const float* qW1    = (const float*)d_in[6];
  const float* qb1    = (const float*)d_in[7];
  const float* qW2    = (const float*)d_in[8];
  const float* qb2    = (const float*)d_in[9];
  const float* muthW  = (const float*)d_in[10];
  const float* muthb  = (const float*)d_in[11];
  const float* lsthW  = (const float*)d_in[12];
  const float* lsthb  = (const float*)d_in[13];
  const float* emW    = (const float*)d_in[14];
  const float* emb    = (const float*)d_in[15];
  const float* Wih    = (const float*)d_in[16];
  const float* Whh    = (const float*)d_in[17];
  const float* bih    = (const float*)d_in[18];
  const float* bhh    = (const float*)d_in[19];
  const float* mueW   = (const float*)d_in[20];
  const float* mueb   = (const float*)d_in[21];
  const float* lseW   = (const float*)d_in[22];
  const float* lseb   = (const float*)d_in[23];
  float* out = (float*)d_out;
  float* ws = (float*)d_ws;

  float* accum = ws + 0;
  float* nb    = ws + 8;
  float* x0    = ws + 1280008;
  float* xproj = ws + 1300008;
  float* hsA   = ws + 1380008;
  float* hsB   = ws + 1400008;
  u16*   whhh  = (u16*)(ws + 1420008);
  float* bsum  = ws + 1660008;
  float* etas  = ws + 1662408;
  float* h1    = ws + 1667408;
  float* h2    = ws + 1769808;
  float* mu_t  = ws + 1872208;
  float* ls_t  = ws + 1878608;
  float* theta = ws + 1885008;
  float* Zrow  = ws + 1891408;
  u16*   A_bf  = (u16*)(ws + 1896408);
  u16*   B_bf  = (u16*)(ws + 2715608);
  u16*   logit = (u16*)(ws + 4333528);

  k_zero<<<1, 64, 0, stream>>>(accum);
  k_nb<<<128, 256, 0, stream>>>(bows, nb);
  k_cvt_f16<<<1875, 256, 0, stream>>>(Whh, whhh, 480000);
  k_bsum<<<10, 256, 0, stream>>>(bih, bhh, bsum, 2400);
  k_prep_A<<<6400, 256, 0, stream>>>(muq, A_bf);
  k_prep_B<<<12640, 256, 0, stream>>>(rho_W, B_bf);

  // x0 = rnn_inp @ eta_map_W^T + eta_map_b
  k_fill<<<79, 256, 0, stream>>>(x0, emb, 200, 20000);
  gemm_abT<0, 5><<<dim3(1, 2, 16), 256, 0, stream>>>(rnn_in, emW, nullptr, x0,
                                                     100, 200, 10000, 10000, 10000, nullptr, nullptr);

  // LSTM layers
  const float* lin[3] = {x0, hsA, hsB};
  float* lout[3] = {hsA, hsB, hsA};
  for (int l = 0; l < 3; ++l) {
    gemm_abT<0, 1><<<dim3(1, 7, 1), 256, 0, stream>>>(lin[l], Wih + l * 160000, bsum + l * 800,
                                                      xproj, 100, 800, 200, 200, 200,
                                                      nullptr, nullptr);
    lstm_scan_reg<<<1, 832, 0, stream>>>(whhh + l * 160000, xproj, lout[l],
                                         mueW, mueb, lseW, lseb, etas, accum, (l == 2) ? 1 : 0);
  }

  // theta encoder
  k_fill<<<400, 256, 0, stream>>>(h1, qb1, 800, 102400);
  gemm_abT<2, 5><<<dim3(1, 7, 24), 256, 0, stream>>>(nb, qW1, nullptr, h1,
                                                     128, 800, 10050, 10000, 10050, times, etas);
  k_relu<<<400, 256, 0, stream>>>(h1, 102400);
  gemm_abT<0, 2><<<dim3(1, 7, 1), 256, 0, stream>>>(h1, qW2, qb2, h2,
                                                    128, 800, 800, 800, 800, nullptr, nullptr);
  gemm_abT<0, 1><<<dim3(1, 1, 1), 256, 0, stream>>>(h2, muthW, muthb, mu_t,
                                                    128, 50, 800, 800, 800, nullptr, nullptr);
  gemm_abT<0, 1><<<dim3(1, 1, 1), 256, 0, stream>>>(h2, lsthW, lsthb, ls_t,
                                                    128, 50, 800, 800, 800, nullptr, nullptr);
  k_theta<<<128, 64, 0, stream>>>(mu_t, ls_t, etas, times, theta, accum);

  // beta logits (bf16 MFMA) + softmax denominators + NLL
  gemm_mfma_bT<<<dim3(40, 79), 256, 0, stream>>>(A_bf, B_bf, logit, 5000, 10000);
  k_rowsum<<<5000, 256, 0, stream>>>(logit, Zrow);
  k_nll<<<dim3(128, 8), 256, 0, stream>>>(logit, Zrow, theta, bows, times, accum);

  k_alpha_kl<<<512, 256, 0, stream>>>(muq, lsq, accum);
  k_final<<<1, 64, 0, stream>>>(accum, out);
}

// Round 7
// 2594.784 us; speedup vs baseline: 1.0857x; 1.0674x over previous
//
#include <hip/hip_runtime.h>

// DETM forward. Round 7: LSTM weights in LDS as int8 (160,000 B fits the
//   163,840 B LDS), sdot4 dot products, dynamic per-step h quantization.
//   Register residency abandoned (R3-R6: allocator pins VGPR budget at
//   64-128 regardless of launch_bounds/waves_per_eu attrs).
//   Eta head split into its own LDS-resident kernel (was streaming 100KB/step
//   of mu/ls weights from global inside the layer-2 scan).

typedef unsigned int u32;
typedef unsigned short u16;
typedef _Float16 f16;
typedef f16 f16x2 __attribute__((ext_vector_type(2)));
typedef short bf16x8 __attribute__((ext_vector_type(8)));
typedef float f32x4 __attribute__((ext_vector_type(4)));

#define LOG_DELTA (-5.2983174f)
#define COEFF 781.25f   // TRAIN_SIZE / B

#if defined(__has_builtin)
#if __has_builtin(__builtin_amdgcn_sdot4)
#define HAVE_SDOT4 1
#endif
#endif

__device__ __forceinline__ float bf2f(u16 a) { return __uint_as_float(((u32)a) << 16); }
__device__ __forceinline__ u16 f2bf(float f) {
  u32 u = __float_as_uint(f);
  u32 r = (u + 0x7fffu + ((u >> 16) & 1u)) >> 16;
  return (u16)r;
}
__device__ __forceinline__ float fdot2(u32 w, u32 h, float acc) {
  return __builtin_amdgcn_fdot2(__builtin_bit_cast(f16x2, w), __builtin_bit_cast(f16x2, h), acc, false);
}
__device__ __forceinline__ int dot4i8(u32 a, u32 b, int c) {
#ifdef HAVE_SDOT4
  return __builtin_amdgcn_sdot4(a, b, c, false);
#else
  int s = c;
  s += ((int)(a << 24) >> 24) * ((int)(b << 24) >> 24);
  s += ((int)(a << 16) >> 24) * ((int)(b << 16) >> 24);
  s += ((int)(a << 8) >> 24) * ((int)(b << 8) >> 24);
  s += ((int)a >> 24) * ((int)b >> 24);
  return s;
#endif
}
__device__ __forceinline__ float sigm(float x) { return 1.f / (1.f + __expf(-x)); }
__device__ __forceinline__ float ftanh(float x) { float t = __expf(2.f * x); return (t - 1.f) / (t + 1.f); }
__device__ __forceinline__ u16 f2h(float x) { return __builtin_bit_cast(u16, (f16)x); }
__device__ __forceinline__ float h2f(u16 x) { return (float)__builtin_bit_cast(f16, x); }
__device__ __forceinline__ void async_load16(const u16* g, u16* l) {
  __builtin_amdgcn_global_load_lds((const __attribute__((address_space(1))) u32*)g,
                                   (__attribute__((address_space(3))) u32*)l, 16, 0, 0);
}

// ---------------- small utility kernels ----------------

__global__ __launch_bounds__(64) void k_zero(float* __restrict__ accum) {
  if (threadIdx.x < 8) accum[threadIdx.x] = 0.f;
}

__global__ __launch_bounds__(256) void k_nb(const float* __restrict__ bows, float* __restrict__ nb) {
  __shared__ float red[256];
  const int b = blockIdx.x, tid = threadIdx.x;
  float s = 0.f;
  for (int v = tid; v < 10000; v += 256) s += bows[b * 10000 + v];
  red[tid] = s; __syncthreads();
  for (int o = 128; o > 0; o >>= 1) { if (tid < o) red[tid] += red[tid + o]; __syncthreads(); }
  const float inv = 1.f / red[0];
  for (int v = tid; v < 10000; v += 256) nb[b * 10000 + v] = bows[b * 10000 + v] * inv;
}

__global__ __launch_bounds__(256) void k_bsum(const float* __restrict__ a, const float* __restrict__ b,
                                              float* __restrict__ o, int n) {
  int i = blockIdx.x * 256 + threadIdx.x;
  if (i < n) o[i] = a[i] + b[i];
}

__global__ __launch_bounds__(256) void k_fill(float* __restrict__ C, const float* __restrict__ bias,
                                              int N, int total) {
  for (int i = blockIdx.x * 256 + threadIdx.x; i < total; i += gridDim.x * 256)
    C[i] = bias[i % N];
}

__global__ __launch_bounds__(256) void k_relu(float* __restrict__ C, int total) {
  for (int i = blockIdx.x * 256 + threadIdx.x; i < total; i += gridDim.x * 256) {
    float v = C[i];
    C[i] = v > 0.f ? v : 0.f;
  }
}

// quantize Whh rows to int8, interleaved layout whq[layer][dword d][row r]
__global__ __launch_bounds__(64) void k_quant_whh(const float* __restrict__ Whh,
                                                  u32* __restrict__ whq, float* __restrict__ rowscale) {
  const int gr = blockIdx.x;          // 0..2399
  const int lane = threadIdx.x;
  __shared__ float wrow[200];
  const float* src = Whh + (size_t)gr * 200;
  float m = 0.f;
  for (int c = lane; c < 200; c += 64) { float v = src[c]; wrow[c] = v; m = fmaxf(m, fabsf(v)); }
  for (int o = 32; o > 0; o >>= 1) m = fmaxf(m, __shfl_down(m, o));
  m = __shfl(m, 0);
  const float qs = (m > 0.f) ? 127.f / m : 0.f;
  __syncthreads();
  const int l = gr / 800, rr = gr - l * 800;
  if (lane < 50) {
    u32 d = 0;
#pragma unroll
    for (int b = 0; b < 4; ++b) {
      int q = __float2int_rn(wrow[lane * 4 + b] * qs);
      q = max(-127, min(127, q));
      d |= ((u32)(q & 0xff)) << (8 * b);
    }
    whq[l * 40000 + lane * 800 + rr] = d;
  }
  if (lane == 0) rowscale[gr] = (m > 0.f) ? m / 127.f : 0.f;
}

// eta-head weights (mu rows 0-49, ls rows 50-99) -> f16, rows of 250
__global__ __launch_bounds__(256) void k_cvt_eta(const float* __restrict__ muW, const float* __restrict__ lsW,
                                                 u16* __restrict__ out) {
  int idx = blockIdx.x * 256 + threadIdx.x;
  if (idx >= 25000) return;
  int r = idx / 250, c = idx - r * 250;
  float v = (r < 50) ? muW[r * 250 + c] : lsW[(r - 50) * 250 + c];
  out[idx] = f2h(v);
}

// bf16 staging for the beta MFMA GEMM
__global__ __launch_bounds__(256) void k_prep_A(const float* __restrict__ muq, u16* __restrict__ Abf) {
  int idx = blockIdx.x * 256 + threadIdx.x;
  if (idx >= 5120 * 320) return;
  int r = idx % 320, m = idx / 320;
  float v = 0.f;
  if (r < 300 && m < 5000) { int t = m / 50, k = m - t * 50; v = muq[k * 30000 + t * 300 + r]; }
  Abf[idx] = f2bf(v);
}
__global__ __launch_bounds__(256) void k_prep_B(const float* __restrict__ rho, u16* __restrict__ Bbf) {
  int idx = blockIdx.x * 256 + threadIdx.x;
  if (idx >= 10112 * 320) return;
  int r = idx % 320, n = idx / 320;
  float v = (r < 300 && n < 10000) ? rho[n * 300 + r] : 0.f;
  Bbf[idx] = f2bf(v);
}

// ---------------- generic fp32 GEMM: C[M,N] = A[M,K] @ B[N,K]^T ----------------

#define GT 128
#define GBK 16

template<int AMODE, int EPI>
__global__ __launch_bounds__(256) void gemm_abT(
    const float* __restrict__ A, const float* __restrict__ Bm,
    const float* __restrict__ bias, float* __restrict__ C,
    int M, int N, int Kd, int lda, int ldb,
    const int* __restrict__ times, const float* __restrict__ etas)
{
  __shared__ __align__(16) float As[GBK][GT + 4];
  __shared__ __align__(16) float Bs[GBK][GT + 4];
  const int tid = threadIdx.x;
  const int tx = tid & 15, ty = tid >> 4;
  const int m_base = blockIdx.x * GT, n_base = blockIdx.y * GT;
  float acc[8][8] = {};
  const int nkt = (Kd + GBK - 1) / GBK;
  const int per = (nkt + gridDim.z - 1) / gridDim.z;
  const int kt0 = blockIdx.z * per;
  const int kt1 = min(nkt, kt0 + per);
  const int lkk = tid & 15;
  const int lmm = tid >> 4;
  for (int kt = kt0; kt < kt1; ++kt) {
    const int kg = kt * GBK + lkk;
#pragma unroll
    for (int i = 0; i < 8; ++i) {
      int m = m_base + lmm + i * 16;
      float v = 0.f;
      if (m < M && kg < Kd) {
        if (AMODE == 0) v = A[(size_t)m * lda + kg];
        else {
          if (kg < 10000) v = A[(size_t)m * 10000 + kg];
          else v = etas[times[m] * 50 + (kg - 10000)];
        }
      }
      As[lkk][lmm + i * 16] = v;
    }
#pragma unroll
    for (int i = 0; i < 8; ++i) {
      int n = n_base + lmm + i * 16;
      float v = 0.f;
      if (n < N && kg < Kd) v = Bm[(size_t)n * ldb + kg];
      Bs[lkk][lmm + i * 16] = v;
    }
    __syncthreads();
#pragma unroll
    for (int kk = 0; kk < GBK; ++kk) {
      const float4* ap = (const float4*)&As[kk][ty * 8];
      const float4* bp = (const float4*)&Bs[kk][tx * 8];
      float4 a0 = ap[0], a1 = ap[1];
      float4 b0 = bp[0], b1 = bp[1];
      float av[8] = {a0.x, a0.y, a0.z, a0.w, a1.x, a1.y, a1.z, a1.w};
      float bv[8] = {b0.x, b0.y, b0.z, b0.w, b1.x, b1.y, b1.z, b1.w};
#pragma unroll
      for (int i = 0; i < 8; ++i)
#pragma unroll
        for (int j = 0; j < 8; ++j) acc[i][j] += av[i] * bv[j];
    }
    __syncthreads();
  }
#pragma unroll
  for (int i = 0; i < 8; ++i) {
    int m = m_base + ty * 8 + i;
    if (m >= M) continue;
#pragma unroll
    for (int j = 0; j < 8; ++j) {
      int n = n_base + tx * 8 + j;
      if (n >= N) continue;
      float v = acc[i][j];
      if (EPI == 1) { C[(size_t)m * N + n] = v + bias[n]; }
      else if (EPI == 2) { v += bias[n]; C[(size_t)m * N + n] = v > 0.f ? v : 0.f; }
      else if (EPI == 5) { atomicAdd(&C[(size_t)m * N + n], v); }
      else { C[(size_t)m * N + n] = v; }
    }
  }
}

// ---------------- beta GEMM: bf16 MFMA ----------------

__global__ __launch_bounds__(256) void gemm_mfma_bT(
    const u16* __restrict__ A, const u16* __restrict__ B, u16* __restrict__ C,
    int M, int N)
{
  __shared__ u16 As[128 * 32];
  __shared__ u16 Bs[128 * 32];
  const int tid = threadIdx.x;
  const int l = tid & 63, w = tid >> 6;
  const int wm = w & 1, wn = w >> 1;
  const int m0 = blockIdx.x * 128, n0 = blockIdx.y * 128;
  f32x4 acc[4][4] = {};
  const int arow = l >> 2;
  const int acol = (l & 3) * 8;
  for (int kt = 0; kt < 10; ++kt) {
    const int k0 = kt * 32;
#pragma unroll
    for (int c = 0; c < 2; ++c) {
      const int i = w + c * 4;
      async_load16(A + (size_t)(m0 + i * 16 + arow) * 320 + k0 + acol, As + i * 512);
      async_load16(B + (size_t)(n0 + i * 16 + arow) * 320 + k0 + acol, Bs + i * 512);
    }
    __syncthreads();
    bf16x8 af[4], bfr[4];
#pragma unroll
    for (int x = 0; x < 4; ++x) {
      af[x]  = *(const bf16x8*)&As[(wm * 64 + x * 16 + (l & 15)) * 32 + (l >> 4) * 8];
      bfr[x] = *(const bf16x8*)&Bs[(wn * 64 + x * 16 + (l & 15)) * 32 + (l >> 4) * 8];
    }
#pragma unroll
    for (int x = 0; x < 4; ++x)
#pragma unroll
      for (int y = 0; y < 4; ++y)
        acc[x][y] = __builtin_amdgcn_mfma_f32_16x16x32_bf16(af[x], bfr[y], acc[x][y], 0, 0, 0);
    __syncthreads();
  }
  const int col = l & 15, quad = l >> 4;
#pragma unroll
  for (int x = 0; x < 4; ++x) {
    const int gmB = m0 + wm * 64 + x * 16 + quad * 4;
#pragma unroll
    for (int y = 0; y < 4; ++y) {
      const int gn = n0 + wn * 64 + y * 16 + col;
      if (gn >= N) continue;
#pragma unroll
      for (int r = 0; r < 4; ++r) {
        const int gm = gmB + r;
        if (gm < M) C[(size_t)gm * N + gn] = f2bf(acc[x][y][r]);
      }
    }
  }
}

// ---------------- LSTM scan: int8 weights LDS-resident ----------------
// 1024 threads; threads 0..799 own gate row `tid` (i:0-199, f:200-399,
// g:400-599, o:600-799). Weights interleaved Wq[d*800+row]: stride 800 dwords
// (= 0 mod 32 banks between d's, 25 mod 32 between rows -> conflict-free).
// h re-quantized to int8 each step with dynamic scale.

__global__ __launch_bounds__(1024) void lstm_scan_lds(
    const u32* __restrict__ whq,       // [50][800] this layer
    const float* __restrict__ rowscale,// [800] this layer
    const float* __restrict__ xproj,   // [100][800]
    float* __restrict__ hseq,          // [100][200]
    u16* __restrict__ hseq16,          // [100][200] f16 copy (layer 2 only)
    const int write16)
{
  __shared__ u32 Wq[40000];     // 160,000 B
  __shared__ u16 pg[800];       // gate pre-acts f16
  __shared__ u32 hq[52];        // h int8 packed
  __shared__ float wmax[16];
  __shared__ float hscale_s[2];
  const int tid = threadIdx.x;
  for (int i = tid; i < 40000; i += 1024) Wq[i] = whq[i];
  if (tid < 52) hq[tid] = 0;
  if (tid == 0) hscale_s[0] = 0.f;
  const int row = tid;
  const int act = (tid < 800);
  const float rs = act ? rowscale[row] : 0.f;
  float c_reg = 0.f;
  __syncthreads();
  for (int t = 0; t < 100; ++t) {
    if (act) {
      const float xp = xproj[t * 800 + row];      // global load, hidden under dots
      const float hdq = hscale_s[0];
      int acc = 0;
#pragma unroll
      for (int G = 0; G < 5; ++G) {
#pragma unroll
        for (int g2 = 0; g2 < 10; ++g2) {
          const int g = G * 10 + g2;
          acc = dot4i8(Wq[g * 800 + row], hq[g], acc);
        }
        __builtin_amdgcn_sched_barrier(0);        // bound live LDS-load regs
      }
      pg[row] = f2h((float)acc * (rs * hdq) + xp);
    }
    __syncthreads();   // pg ready; all lanes done reading hq/hscale
    float hv = 0.f;
    if (tid < 200) {
      float gi = sigm(h2f(pg[tid]));
      float gf = sigm(h2f(pg[200 + tid]));
      float gg = ftanh(h2f(pg[400 + tid]));
      float go = sigm(h2f(pg[600 + tid]));
      c_reg = gf * c_reg + gi * gg;
      hv = go * ftanh(c_reg);
      hseq[t * 200 + tid] = hv;
      if (write16) hseq16[t * 200 + tid] = f2h(hv);
    }
    // block-wide max|h| (only waves 0-3 hold h; others contribute 0)
    float m = fabsf(hv);
    for (int o = 32; o > 0; o >>= 1) m = fmaxf(m, __shfl_down(m, o));
    if ((tid & 63) == 0) wmax[tid >> 6] = m;
    __syncthreads();   // wmax ready, pg consumed
    if (tid < 200) {
      const float hm = fmaxf(fmaxf(wmax[0], wmax[1]), fmaxf(wmax[2], wmax[3]));
      const float qs = (hm > 0.f) ? 127.f / hm : 0.f;
      int q = __float2int_rn(hv * qs);
      q = max(-127, min(127, q));
      ((signed char*)hq)[tid] = (signed char)q;
      if (tid == 0) hscale_s[0] = (hm > 0.f) ? hm / 127.f : 0.f;
    }
    __syncthreads();   // hq + hscale ready for next step
  }
}

// ---------------- eta scan: f16 weights + h-seq LDS-resident ----------------
// 512 threads, single WG. x = [o_t(200), eta_prev(50)] f16; dots by 400
// threads (r = tid%100 -> row, s4 = tid/100 -> quarter; row stride 125 dwords
// = 29 mod 32 banks -> conflict-free).

__global__ __launch_bounds__(512) void eta_scan(
    const u16* __restrict__ etaWh,  // [100][250] f16 (mu rows 0-49, ls 50-99)
    const float* __restrict__ mub, const float* __restrict__ lsb,
    const u16* __restrict__ hseq16, // [100][200] f16
    float* __restrict__ etas, float* __restrict__ accum)
{
  __shared__ __align__(4) u16 EW[25000];   // 50,000 B
  __shared__ __align__(4) u16 HS[20000];   // 40,000 B
  __shared__ __align__(4) u16 xh[252];
  __shared__ float pc[400];
  __shared__ float mu_ls[100];
  __shared__ float bias[100];
  __shared__ float eta_f[52];
  const int tid = threadIdx.x;
  for (int i = tid; i < 12500; i += 512) ((u32*)EW)[i] = ((const u32*)etaWh)[i];
  for (int i = tid; i < 10000; i += 512) ((u32*)HS)[i] = ((const u32*)hseq16)[i];
  if (tid < 100) bias[tid] = (tid < 50) ? mub[tid] : lsb[tid - 50];
  if (tid < 52) eta_f[tid] = 0.f;
  if (tid < 252) xh[tid] = 0;
  float klacc = 0.f;
  const int r = tid % 100, s4 = tid / 100;    // for dot phase (tid<400)
  const int q0 = s4 * 32, q1 = min(125, q0 + 32);
  __syncthreads();
  for (int t = 0; t < 100; ++t) {
    if (tid < 100) ((u32*)xh)[tid] = ((const u32*)HS)[t * 100 + tid];  // o_t
    __syncthreads();
    if (tid < 400) {
      float acc = 0.f;
      const u32* Wr = (const u32*)EW;  // row r: dwords [r*125, r*125+125)
      const u32* X2 = (const u32*)xh;
      for (int q = q0; q < q1; ++q) acc = fdot2(Wr[r * 125 + q], X2[q], acc);
      pc[s4 * 100 + r] = acc;
    }
    __syncthreads();
    if (tid < 100)
      mu_ls[tid] = pc[tid] + pc[100 + tid] + pc[200 + tid] + pc[300 + tid] + bias[tid];
    __syncthreads();
    if (tid < 50) {
      float mu = mu_ls[tid], ls = mu_ls[50 + tid], ep = eta_f[tid];
      float pls = (t == 0) ? 0.f : LOG_DELTA;
      float pv = __expf(pls) + 1e-6f;
      float d = mu - ep;
      klacc += 0.5f * ((__expf(ls) + d * d) / pv - 1.f + pls - ls);
      etas[t * 50 + tid] = mu;
      eta_f[tid] = mu;
      xh[200 + tid] = f2h(mu);
    }
    __syncthreads();
  }
  if (tid < 64) {
    for (int o = 32; o > 0; o >>= 1) klacc += __shfl_down(klacc, o);
    if (tid == 0) accum[0] = klacc;
  }
}

// ---------------- theta head ----------------

__global__ __launch_bounds__(64) void k_theta(const float* __restrict__ mu_t, const float* __restrict__ ls_t,
                                              const float* __restrict__ etas, const int* __restrict__ times,
                                              float* __restrict__ theta, float* __restrict__ accum) {
  const int b = blockIdx.x, lane = threadIdx.x;
  float m_ = 0.f, l_ = 0.f, e_ = 0.f, mx = -1e30f;
  if (lane < 50) {
    m_ = mu_t[b * 50 + lane];
    l_ = ls_t[b * 50 + lane];
    e_ = etas[times[b] * 50 + lane];
    mx = m_;
  }
  for (int o = 32; o > 0; o >>= 1) mx = fmaxf(mx, __shfl_down(mx, o));
  mx = __shfl(mx, 0);
  float ex = (lane < 50) ? __expf(m_ - mx) : 0.f;
  float sum = ex;
  for (int o = 32; o > 0; o >>= 1) sum += __shfl_down(sum, o);
  sum = __shfl(sum, 0);
  if (lane < 50) theta[b * 50 + lane] = ex / sum;
  float kl = 0.f;
  if (lane < 50) {
    float d = m_ - e_;
    kl = 0.5f * ((__expf(l_) + d * d) / (1.f + 1e-6f) - 1.f - l_);
  }
  for (int o = 32; o > 0; o >>= 1) kl += __shfl_down(kl, o);
  if (lane == 0) atomicAdd(accum + 1, kl);
}

// ---------------- softmax denominators ----------------

__global__ __launch_bounds__(256) void k_rowsum(const u16* __restrict__ logit, float* __restrict__ Z) {
  const int r = blockIdx.x, tid = threadIdx.x;
  const u32* row = (const u32*)(logit + (size_t)r * 10000);
  __shared__ float red[256];
  float s = 0.f;
  for (int v = tid; v < 5000; v += 256) {
    u32 p = row[v];
    s += __expf(bf2f((u16)(p & 0xffffu))) + __expf(bf2f((u16)(p >> 16)));
  }
  red[tid] = s; __syncthreads();
  for (int o = 128; o > 0; o >>= 1) { if (tid < o) red[tid] += red[tid + o]; __syncthreads(); }
  if (tid == 0) Z[r] = red[0];
}

// ---------------- NLL ----------------

__global__ __launch_bounds__(256) void k_nll(const u16* __restrict__ logit, const float* __restrict__ Z,
                                             const float* __restrict__ theta, const float* __restrict__ bows,
                                             const int* __restrict__ times, float* __restrict__ accum) {
  const int b = blockIdx.x, seg = blockIdx.y, tid = threadIdx.x;
  const int t = times[b];
  __shared__ float c2[52];
  __shared__ float red[256];
  if (tid < 50) c2[tid] = theta[b * 50 + tid] / Z[t * 50 + tid];
  __syncthreads();
  float part = 0.f;
  const int v0 = seg * 1250, v1 = v0 + 1250;
  const u16* base = logit + (size_t)t * 500000;
  for (int v = v0 + tid; v < v1; v += 256) {
    float ssv = 1e-12f;
#pragma unroll
    for (int k = 0; k < 50; ++k) ssv += c2[k] * __expf(bf2f(base[k * 10000 + v]));
    part += bows[b * 10000 + v] * __logf(ssv);
  }
  red[tid] = part; __syncthreads();
  for (int o = 128; o > 0; o >>= 1) { if (tid < o) red[tid] += red[tid + o]; __syncthreads(); }
  if (tid == 0) atomicAdd(accum + 3, -red[0]);
}

// ---------------- kl_alpha ----------------

__global__ __launch_bounds__(256) void k_alpha_kl(const float* __restrict__ muq, const float* __restrict__ lsq,
                                                  float* __restrict__ accum) {
  __shared__ float red[256];
  const int tid = threadIdx.x;
  float s = 0.f;
  for (int i = blockIdx.x * 256 + tid; i < 1500000; i += gridDim.x * 256) {
    int r = i % 300;
    int tk = i / 300;
    int k = tk % 50;
    int t = tk / 50;
    size_t idx = (size_t)k * 30000 + (size_t)t * 300 + r;
    float mu = muq[idx], ls = lsq[idx];
    float pm = 0.f, pls = 0.f;
    if (t > 0) { pm = muq[idx - 300]; pls = LOG_DELTA; }
    float d = mu - pm;
    s += 0.5f * ((__expf(ls) + d * d) / (__expf(pls) + 1e-6f) - 1.f + pls - ls);
  }
  red[tid] = s; __syncthreads();
  for (int o = 128; o > 0; o >>= 1) { if (tid < o) red[tid] += red[tid + o]; __syncthreads(); }
  if (tid == 0) atomicAdd(accum + 2, red[0]);
}

// ---------------- final combine ----------------

__global__ __launch_bounds__(64) void k_final(const float* __restrict__ accum, float* __restrict__ out) {
  if (threadIdx.x == 0) {
    float nll = accum[3] * COEFF;
    float kl_eta = accum[0];
    float kl_theta = accum[1] * COEFF;
    float kl_alpha = accum[2];
    out[0] = nll + kl_eta + kl_theta + kl_alpha;
    out[1] = nll;
    out[2] = kl_eta;
    out[3] = kl_theta;
    out[4] = kl_alpha;
  }
}

// ---------------- launcher ----------------

extern "C" void kernel_launch(void* const* d_in, const int* in_sizes, int n_in,
                              void* d_out, int out_size, void* d_ws, size_t ws_size,
                              hipStream_t stream) {
  (void)in_sizes; (void)n_in; (void)out_size; (void)ws_size;
  const float* bows   = (const float*)d_in[0];
  const int*   times  = (const int*)d_in[1];
  const float* rnn_in = (const float*)d_in[2];
  const float* rho_W  = (const float*)d_in[3];
  const float* muq    = (const float*)d_in[4];
  const float* lsq    = (const float*)d_in[5];
  const float* qW1    = (const float*)d_in[6];
  const float* qb1    = (const float*)d_in[7];
  const float* qW2    = (const float*)d_in[8];
  const float* qb2    = (const float*)d_in[9];
  const float* muthW  = (const float*)d_in[10];
  const float* muthb  = (const float*)d_in[11];
  const float* lsthW  = (const float*)d_in[12];
  const float* lsthb  = (const float*)d_in[13];
  const float* emW    = (const float*)d_in[14];
  const float* emb    = (const float*)d_in[15];
  const float* Wih    = (const float*)d_in[16];
  const float* Whh    = (const float*)d_in[17];
  const float* bih    = (const float*)d_in[18];
  const float* bhh    = (const float*)d_in[19];
  const float* mueW   = (const float*)d_in[20];
  const float* mueb   = (const float*)d_in[21];
  const float* lseW   = (const float*)d_in[22];
  const float* lseb   = (const float*)d_in[23];
  float* out = (float*)d_out;
  float* ws = (float*)d_ws;

  float* accum = ws + 0;
  float* nb    = ws + 8;
  float* x0    = ws + 1280008;
  float* xproj = ws + 1300008;
  float* hsA   = ws + 1380008;
  float* hsB   = ws + 1400008;
  u32*   whq   = (u32*)(ws + 1420008);         // 120,000 u32 (3 layers)
  float* rowsc = ws + 1540008;                 // 2400
  u16*   etaWh = (u16*)(ws + 1545008);         // 25,000 u16
  float* hsC   = ws + 1558008;                 // 20,000
  u16*   hs16  = (u16*)(ws + 1580008);         // 20,000 u16
  float* bsum  = ws + 1660008;
  float* etas  = ws + 1662408;
  float* h1    = ws + 1667408;
  float* h2    = ws + 1769808;
  float* mu_t  = ws + 1872208;
  float* ls_t  = ws + 1878608;
  float* theta = ws + 1885008;
  float* Zrow  = ws + 1891408;
  u16*   A_bf  = (u16*)(ws + 1896408);
  u16*   B_bf  = (u16*)(ws + 2715608);
  u16*   logit = (u16*)(ws + 4333528);

  k_zero<<<1, 64, 0, stream>>>(accum);
  k_nb<<<128, 256, 0, stream>>>(bows, nb);
  k_quant_whh<<<2400, 64, 0, stream>>>(Whh, whq, rowsc);
  k_bsum<<<10, 256, 0, stream>>>(bih, bhh, bsum, 2400);
  k_cvt_eta<<<98, 256, 0, stream>>>(mueW, lseW, etaWh);
  k_prep_A<<<6400, 256, 0, stream>>>(muq, A_bf);
  k_prep_B<<<12640, 256, 0, stream>>>(rho_W, B_bf);

  // x0 = rnn_inp @ eta_map_W^T + eta_map_b
  k_fill<<<79, 256, 0, stream>>>(x0, emb, 200, 20000);
  gemm_abT<0, 5><<<dim3(1, 2, 16), 256, 0, stream>>>(rnn_in, emW, nullptr, x0,
                                                     100, 200, 10000, 10000, 10000, nullptr, nullptr);

  // LSTM layers (int8-LDS scans)
  const float* lin[3] = {x0, hsA, hsB};
  float* lout[3] = {hsA, hsB, hsC};
  for (int l = 0; l < 3; ++l) {
    gemm_abT<0, 1><<<dim3(1, 7, 1), 256, 0, stream>>>(lin[l], Wih + l * 160000, bsum + l * 800,
                                                      xproj, 100, 800, 200, 200, 200,
                                                      nullptr, nullptr);
    lstm_scan_lds<<<1, 1024, 0, stream>>>(whq + l * 40000, rowsc + l * 800, xproj,
                                          lout[l], hs16, (l == 2) ? 1 : 0);
  }
  // eta head (sequential over t, LDS-resident weights + h-seq)
  eta_scan<<<1, 512, 0, stream>>>(etaWh, mueb, lseb, hs16, etas, accum);

  // theta encoder
  k_fill<<<400, 256, 0, stream>>>(h1, qb1, 800, 102400);
  gemm_abT<2, 5><<<dim3(1, 7, 24), 256, 0, stream>>>(nb, qW1, nullptr, h1,
                                                     128, 800, 10050, 10000, 10050, times, etas);
  k_relu<<<400, 256, 0, stream>>>(h1, 102400);
  gemm_abT<0, 2><<<dim3(1, 7, 1), 256, 0, stream>>>(h1, qW2, qb2, h2,
                                                    128, 800, 800, 800, 800, nullptr, nullptr);
  gemm_abT<0, 1><<<dim3(1, 1, 1), 256, 0, stream>>>(h2, muthW, muthb, mu_t,
                                                    128, 50, 800, 800, 800, nullptr, nullptr);
  gemm_abT<0, 1><<<dim3(1, 1, 1), 256, 0, stream>>>(h2, lsthW, lsthb, ls_t,
                                                    128, 50, 800, 800, 800, nullptr, nullptr);
  k_theta<<<128, 64, 0, stream>>>(mu_t, ls_t, etas, times, theta, accum);

  // beta logits (bf16 MFMA) + softmax denominators + NLL
  gemm_mfma_bT<<<dim3(40, 79), 256, 0, stream>>>(A_bf, B_bf, logit, 5000, 10000);
  k_rowsum<<<5000, 256, 0, stream>>>(logit, Zrow);
  k_nll<<<dim3(128, 8), 256, 0, stream>>>(logit, Zrow, theta, bows, times, accum);

  k_alpha_kl<<<512, 256, 0, stream>>>(muq, lsq, accum);
  k_final<<<1, 64, 0, stream>>>(accum, out);
}